// Round 5
// baseline (332.750 us; speedup 1.0000x reference)
//
#include <hip/hip_runtime.h>
#include <cstdint>
#include <cstddef>

// ---------------------------------------------------------------------------
// GCN 3-layer forward, CSR-gather formulation (no f32 atomics, no csr_nrm):
//   out[d] = dinv[d] * ( sum_{s in N(d)} T'[s] + T'[d] ) + b,
//   with T'[r] = dinv[r] * (X[r] @ W)   (scale fused into matmul epilogue).
// CSR build per call: count -> 3-phase scan (+dinv fused) -> fill (src only).
// Round 4: dropped csr_nrm (halves fill scatter traffic, was 104 MB writes),
// float4 weight broadcasts in matmul, dinv fused into scan3.
// ---------------------------------------------------------------------------

__device__ __forceinline__ int eidx_at(const void* p, long long i, int is64) {
  if (is64) return (int)((const long long*)p)[i];
  return ((const int*)p)[i];
}

__global__ void k_flag(const void* eidx, int* flag) {
  // int64 node indices are all < 1e5; int32 data read as u64 has a random
  // index in the high word -> huge values. One wave checks 256 words.
  const unsigned long long* p = (const unsigned long long*)eidx;
  int lane = threadIdx.x & 63;
  int bad = 0;
#pragma unroll
  for (int i = 0; i < 4; ++i) bad |= (p[lane + 64 * i] > 1000000000ULL) ? 1 : 0;
  int any_bad = __any(bad);
  if (lane == 0) *flag = any_bad ? 0 : 1;
}

// histogram of dst (real edges only; self-loop handled via dinv/epilogue)
__global__ void k_count(const void* eidx, const int* flag, int* cnt, int E) {
  int e = blockIdx.x * blockDim.x + threadIdx.x;
  if (e >= E) return;
  int is64 = *flag;
  int d = eidx_at(eidx, (long long)E + e, is64);
  atomicAdd(&cnt[d], 1);
}

// ---- 3-phase scan: 1024 elems per block (256 thr x 4) ----
__global__ __launch_bounds__(256) void k_scan1(const int* __restrict__ cnt,
                                               int* __restrict__ part, int n) {
  int b = blockIdx.x, t = threadIdx.x;
  int base = b * 1024 + t * 4;
  int s = 0;
#pragma unroll
  for (int i = 0; i < 4; ++i) { int idx = base + i; if (idx < n) s += cnt[idx]; }
  __shared__ int sh[256];
  sh[t] = s;
  __syncthreads();
  for (int off = 128; off > 0; off >>= 1) {
    if (t < off) sh[t] += sh[t + off];
    __syncthreads();
  }
  if (t == 0) part[b] = sh[0];
}

// single small block: exclusive-scan part[0..nb), write rowptr[n]=E
__global__ __launch_bounds__(1024) void k_scan2(int* __restrict__ part, int nb,
                                                int* __restrict__ rowptr, int n, int E) {
  int t = threadIdx.x;
  __shared__ int sh[1024];
  int v = (t < nb) ? part[t] : 0;
  sh[t] = v;
  __syncthreads();
  for (int off = 1; off < 1024; off <<= 1) {
    int x = (t >= off) ? sh[t - off] : 0;
    __syncthreads();
    sh[t] += x;
    __syncthreads();
  }
  if (t < nb) part[t] = sh[t] - v;  // exclusive
  if (t == 0) rowptr[n] = E;
}

// local scan + offsets; also computes dinv = rsqrt(cnt+1)
__global__ __launch_bounds__(256) void k_scan3(const int* __restrict__ cnt,
                                               const int* __restrict__ part,
                                               int* __restrict__ rowptr,
                                               int* __restrict__ cursor,
                                               float* __restrict__ dinv, int n) {
  int b = blockIdx.x, t = threadIdx.x;
  int base = b * 1024 + t * 4;
  int v[4];
  int s = 0;
#pragma unroll
  for (int i = 0; i < 4; ++i) {
    int idx = base + i;
    v[i] = (idx < n) ? cnt[idx] : 0;
    s += v[i];
  }
  __shared__ int sh[256];
  sh[t] = s;
  __syncthreads();
  for (int off = 1; off < 256; off <<= 1) {
    int x = (t >= off) ? sh[t - off] : 0;
    __syncthreads();
    sh[t] += x;
    __syncthreads();
  }
  int run = part[b] + sh[t] - s;  // exclusive offset for this thread
#pragma unroll
  for (int i = 0; i < 4; ++i) {
    int idx = base + i;
    if (idx < n) {
      rowptr[idx] = run;
      cursor[idx] = run;
      dinv[idx] = rsqrtf((float)(v[i] + 1));
    }
    run += v[i];
  }
}

__global__ void k_fill(const void* eidx, const int* flag, int* cursor,
                       int* __restrict__ csr_src, int E) {
  int e = blockIdx.x * blockDim.x + threadIdx.x;
  if (e >= E) return;
  int is64 = *flag;
  int s = eidx_at(eidx, e, is64);
  int d = eidx_at(eidx, (long long)E + e, is64);
  int pos = atomicAdd(&cursor[d], 1);
  csr_src[pos] = s;
}

// T'[r] = dinv[r] * (X[r] @ W).  One thread per row; W as float4 in LDS
// (wave-uniform broadcast reads, 1 ds_read_b128 per 4 FMAs).
template <int COUT>
__global__ __launch_bounds__(256) void k_matmul(const float* __restrict__ X,
                                                const float* __restrict__ W,
                                                const float* __restrict__ dinv,
                                                float* __restrict__ T, int n) {
  const int C4 = COUT / 4;
  __shared__ float4 Ws[64 * C4];
  for (int i = threadIdx.x; i < 64 * C4; i += blockDim.x)
    Ws[i] = ((const float4*)W)[i];
  __syncthreads();
  int r = blockIdx.x * blockDim.x + threadIdx.x;
  if (r >= n) return;
  float4 acc[C4];
#pragma unroll
  for (int j = 0; j < C4; ++j) acc[j] = make_float4(0.f, 0.f, 0.f, 0.f);
  const float4* xr = (const float4*)(X + (size_t)r * 64);
#pragma unroll
  for (int k4 = 0; k4 < 16; ++k4) {
    float4 xv = xr[k4];
    const float xs[4] = {xv.x, xv.y, xv.z, xv.w};
#pragma unroll
    for (int c = 0; c < 4; ++c) {
      float xk = xs[c];
      const float4* wrow = &Ws[(k4 * 4 + c) * C4];
#pragma unroll
      for (int j = 0; j < C4; ++j) {
        float4 w = wrow[j];
        acc[j].x = fmaf(xk, w.x, acc[j].x);
        acc[j].y = fmaf(xk, w.y, acc[j].y);
        acc[j].z = fmaf(xk, w.z, acc[j].z);
        acc[j].w = fmaf(xk, w.w, acc[j].w);
      }
    }
  }
  float dr = dinv[r];
  float4* tr = (float4*)(T + (size_t)r * COUT);
#pragma unroll
  for (int j = 0; j < C4; ++j)
    tr[j] = make_float4(acc[j].x * dr, acc[j].y * dr, acc[j].z * dr, acc[j].w * dr);
}

// One wave per dst row: acc = sum T'[src[j]] (batched 8/4/1, independent
// loads), then out = dinv[row]*(acc + T'[row]) + b, optional relu.
template <int COUT, bool RELU>
__global__ __launch_bounds__(256) void k_gather(const float* __restrict__ T,
                                                const int* __restrict__ rowptr,
                                                const int* __restrict__ csr_src,
                                                const float* __restrict__ dinv,
                                                const float* __restrict__ b,
                                                float* __restrict__ out, int n) {
  int wave = blockIdx.x * (blockDim.x >> 6) + (threadIdx.x >> 6);
  int lane = threadIdx.x & 63;
  int row = __builtin_amdgcn_readfirstlane(wave);
  if (row >= n) return;
  int beg = rowptr[row];
  int end = rowptr[row + 1];
  float dr = dinv[row];
  float a0 = 0.f, a1 = 0.f, a2 = 0.f, a3 = 0.f;
  int j = beg;
  if (lane < COUT) {
    for (; j + 8 <= end; j += 8) {
      int s0 = csr_src[j + 0], s1 = csr_src[j + 1], s2 = csr_src[j + 2], s3 = csr_src[j + 3];
      int s4 = csr_src[j + 4], s5 = csr_src[j + 5], s6 = csr_src[j + 6], s7 = csr_src[j + 7];
      float t0 = T[(size_t)s0 * COUT + lane];
      float t1 = T[(size_t)s1 * COUT + lane];
      float t2 = T[(size_t)s2 * COUT + lane];
      float t3 = T[(size_t)s3 * COUT + lane];
      float t4 = T[(size_t)s4 * COUT + lane];
      float t5 = T[(size_t)s5 * COUT + lane];
      float t6 = T[(size_t)s6 * COUT + lane];
      float t7 = T[(size_t)s7 * COUT + lane];
      a0 += t0; a1 += t1; a2 += t2; a3 += t3;
      a0 += t4; a1 += t5; a2 += t6; a3 += t7;
    }
    if (j + 4 <= end) {
      int s0 = csr_src[j + 0], s1 = csr_src[j + 1], s2 = csr_src[j + 2], s3 = csr_src[j + 3];
      float t0 = T[(size_t)s0 * COUT + lane];
      float t1 = T[(size_t)s1 * COUT + lane];
      float t2 = T[(size_t)s2 * COUT + lane];
      float t3 = T[(size_t)s3 * COUT + lane];
      a0 += t0; a1 += t1; a2 += t2; a3 += t3;
      j += 4;
    }
    for (; j < end; ++j) {
      int s = csr_src[j];
      a0 += T[(size_t)s * COUT + lane];
    }
    float acc = (a0 + a1) + (a2 + a3);
    float v = fmaf(dr, acc + T[(size_t)row * COUT + lane], b[lane]);
    if (RELU) v = fmaxf(v, 0.f);
    out[(size_t)row * COUT + lane] = v;
  }
}

extern "C" void kernel_launch(void* const* d_in, const int* in_sizes, int n_in,
                              void* d_out, int out_size, void* d_ws, size_t ws_size,
                              hipStream_t stream) {
  const float* x  = (const float*)d_in[0];
  const void*  ei = d_in[1];
  const float* W1 = (const float*)d_in[2];
  const float* b1 = (const float*)d_in[3];
  const float* W2 = (const float*)d_in[4];
  const float* b2 = (const float*)d_in[5];
  const float* W3 = (const float*)d_in[6];
  const float* b3 = (const float*)d_in[7];
  float* out = (float*)d_out;

  const int n = in_sizes[0] / 64;   // 100000
  const int E = in_sizes[1] / 2;    // 1000000

  char* ws = (char*)d_ws;
  size_t off = 0;
  auto carve = [&](size_t bytes) -> void* {
    void* p = ws + off;
    off = (off + bytes + 255) & ~(size_t)255;
    return p;
  };
  int*   flag    = (int*)carve(16);
  int*   cnt     = (int*)carve(sizeof(int) * n);
  float* dinv    = (float*)carve(sizeof(float) * n);
  int*   rowptr  = (int*)carve(sizeof(int) * (n + 1));
  int*   cursor  = (int*)carve(sizeof(int) * n);
  int*   part    = (int*)carve(sizeof(int) * 1024);
  int*   csr_src = (int*)carve(sizeof(int) * E);
  float* T       = (float*)carve(sizeof(float) * (size_t)n * 64);
  float* A       = (float*)carve(sizeof(float) * (size_t)n * 64);

  const int B = 256;
  const int gN = (n + B - 1) / B;
  const int gE = (E + B - 1) / B;
  const int gW = (n + 3) / 4;            // 4 waves/block, 1 wave/row
  const int nb = (n + 1023) / 1024;      // scan blocks (98)

  // ---- graph preprocessing (once per call, shared by all 3 layers) ----
  k_flag<<<1, 64, 0, stream>>>(ei, flag);
  hipMemsetAsync(cnt, 0, sizeof(int) * n, stream);
  k_count<<<gE, B, 0, stream>>>(ei, flag, cnt, E);
  k_scan1<<<nb, B, 0, stream>>>(cnt, part, n);
  k_scan2<<<1, 1024, 0, stream>>>(part, nb, rowptr, n, E);
  k_scan3<<<nb, B, 0, stream>>>(cnt, part, rowptr, cursor, dinv, n);
  k_fill<<<gE, B, 0, stream>>>(ei, flag, cursor, csr_src, E);

  // ---- layer 1: x -> A ----
  k_matmul<64><<<gN, B, 0, stream>>>(x, W1, dinv, T, n);
  k_gather<64, true><<<gW, B, 0, stream>>>(T, rowptr, csr_src, dinv, b1, A, n);

  // ---- layer 2: A -> A ----
  k_matmul<64><<<gN, B, 0, stream>>>(A, W2, dinv, T, n);
  k_gather<64, true><<<gW, B, 0, stream>>>(T, rowptr, csr_src, dinv, b2, A, n);

  // ---- layer 3: A -> out ----
  k_matmul<32><<<gN, B, 0, stream>>>(A, W3, dinv, T, n);
  k_gather<32, false><<<gW, B, 0, stream>>>(T, rowptr, csr_src, dinv, b3, out, n);
}

// Round 6
// 249.473 us; speedup vs baseline: 1.3338x; 1.3338x over previous
//
#include <hip/hip_runtime.h>
#include <cstdint>
#include <cstddef>

// ---------------------------------------------------------------------------
// GCN 3-layer forward, CSR-gather formulation:
//   out[d] = dinv[d] * ( sum_{s in N(d)} T'[s] + T'[d] ) + b,
//   with T'[r] = dinv[r] * (X[r] @ W)   (scale fused into matmul epilogue).
// Round 5: CSR build rebuilt as a 2-level bucket counting sort. Round-4
// lesson: global-atomic random scatter (k_count/k_fill) is line/atomic-bound
// (74 us at 1 TB/s, VALU 0.4%), independent of payload size. Now all
// fine-grained atomics are LDS-local; global writes are block-private ranges.
//   S1  per-block bucket histogram (bucket = dst>>9, 196 buckets)
//   S2a scan bucket totals; S2b scan per-(block,bucket) -> disjoint ranges
//   S3  scatter packed (dstlow,src) into per-block bucket ranges (LDS cursors)
//   S4  per-bucket: LDS hist+scan -> rowptr/dinv; scatter csr_src within the
//       bucket's 20KB window (lines assembled in L2; coalesced at eviction)
// ---------------------------------------------------------------------------

#define CH 4096      // edges per S1/S3 block
#define BSHIFT 9     // 512 dsts per bucket
#define BSIZE 512
// assumes n <= 131072 (src fits 17 bits, NB <= 256); n = 100000 here.

__device__ __forceinline__ int eidx_at(const void* p, long long i, int is64) {
  if (is64) return (int)((const long long*)p)[i];
  return ((const int*)p)[i];
}

__global__ void k_flag(const void* eidx, int* flag) {
  // int64 node indices are all < 1e5; int32 data read as u64 has a random
  // index in the high word -> huge values. One wave checks 256 words.
  const unsigned long long* p = (const unsigned long long*)eidx;
  int lane = threadIdx.x & 63;
  int bad = 0;
#pragma unroll
  for (int i = 0; i < 4; ++i) bad |= (p[lane + 64 * i] > 1000000000ULL) ? 1 : 0;
  int any_bad = __any(bad);
  if (lane == 0) *flag = any_bad ? 0 : 1;
}

// S1: per-block histogram over buckets (LDS atomics only, 1 global add/bucket)
__global__ __launch_bounds__(256) void k_s1(const void* eidx, const int* flag,
                                            int* __restrict__ blk_off,
                                            int* __restrict__ bucket_tot,
                                            int E, int NB) {
  __shared__ int h[256];
  int t = threadIdx.x, blk = blockIdx.x;
  if (t < NB) h[t] = 0;
  __syncthreads();
  int is64 = *flag;
  int lo = blk * CH, hi = min(lo + CH, E);
  for (int i = lo + t; i < hi; i += 256) {
    int d = eidx_at(eidx, (long long)E + i, is64);
    atomicAdd(&h[d >> BSHIFT], 1);
  }
  __syncthreads();
  if (t < NB) {
    blk_off[(size_t)blk * NB + t] = h[t];
    atomicAdd(&bucket_tot[t], h[t]);
  }
}

// S2a: exclusive scan of bucket totals (NB <= 256)
__global__ __launch_bounds__(256) void k_s2a(const int* __restrict__ bucket_tot,
                                             int* __restrict__ bucket_base,
                                             int* __restrict__ rowptr,
                                             int NB, int n, int E) {
  int t = threadIdx.x;
  __shared__ int sh[256];
  int v = (t < NB) ? bucket_tot[t] : 0;
  sh[t] = v;
  __syncthreads();
  for (int off = 1; off < 256; off <<= 1) {
    int x = (t >= off) ? sh[t - off] : 0;
    __syncthreads();
    sh[t] += x;
    __syncthreads();
  }
  if (t < NB) bucket_base[t] = sh[t] - v;
  if (t == 0) { bucket_base[NB] = E; rowptr[n] = E; }
}

// S2b: per bucket, scan its per-block counts -> exclusive write ranges
__global__ __launch_bounds__(256) void k_s2b(int* __restrict__ blk_off,
                                             const int* __restrict__ bucket_base,
                                             int nblk, int NB) {
  int b = blockIdx.x, t = threadIdx.x;
  __shared__ int sh[256];
  __shared__ int carry;
  if (t == 0) carry = bucket_base[b];
  __syncthreads();
  for (int tile = 0; tile < nblk; tile += 256) {
    int i = tile + t;
    int v = (i < nblk) ? blk_off[(size_t)i * NB + b] : 0;
    sh[t] = v;
    __syncthreads();
    for (int off = 1; off < 256; off <<= 1) {
      int x = (t >= off) ? sh[t - off] : 0;
      __syncthreads();
      sh[t] += x;
      __syncthreads();
    }
    int c = carry;
    if (i < nblk) blk_off[(size_t)i * NB + b] = c + sh[t] - v;
    int tot = sh[255];
    __syncthreads();
    if (t == 0) carry = c + tot;
    __syncthreads();
  }
}

// S3: scatter packed edges into this block's disjoint bucket ranges
__global__ __launch_bounds__(256) void k_s3(const void* eidx, const int* flag,
                                            const int* __restrict__ blk_off,
                                            unsigned int* __restrict__ packed,
                                            int E, int NB) {
  __shared__ int cur[256];
  int t = threadIdx.x, blk = blockIdx.x;
  if (t < NB) cur[t] = blk_off[(size_t)blk * NB + t];
  __syncthreads();
  int is64 = *flag;
  int lo = blk * CH, hi = min(lo + CH, E);
  for (int i = lo + t; i < hi; i += 256) {
    int s = eidx_at(eidx, i, is64);
    int d = eidx_at(eidx, (long long)E + i, is64);
    int pos = atomicAdd(&cur[d >> BSHIFT], 1);  // LDS atomic
    packed[pos] = ((unsigned)(d & (BSIZE - 1)) << 17) | (unsigned)s;
  }
}

// S4: one block per bucket. LDS hist over 512 local dsts -> rowptr/dinv
// (coalesced), then scatter csr_src within the bucket's window.
__global__ __launch_bounds__(256) void k_s4(const unsigned int* __restrict__ packed,
                                            const int* __restrict__ bucket_base,
                                            int* __restrict__ rowptr,
                                            float* __restrict__ dinv,
                                            int* __restrict__ csr_src, int n) {
  int b = blockIdx.x, t = threadIdx.x;
  int lo = bucket_base[b], hi = bucket_base[b + 1];
  __shared__ int h[BSIZE];
  __shared__ int ps[256];
  __shared__ int cur[BSIZE];
  h[2 * t] = 0; h[2 * t + 1] = 0;
  __syncthreads();
  for (int i = lo + t; i < hi; i += 256)
    atomicAdd(&h[packed[i] >> 17], 1);
  __syncthreads();
  int a0 = h[2 * t], a1 = h[2 * t + 1];
  ps[t] = a0 + a1;
  __syncthreads();
  for (int off = 1; off < 256; off <<= 1) {
    int x = (t >= off) ? ps[t - off] : 0;
    __syncthreads();
    ps[t] += x;
    __syncthreads();
  }
  int pexcl = ps[t] - (a0 + a1);
  int e0 = lo + pexcl, e1 = lo + pexcl + a0;
  cur[2 * t] = e0;
  cur[2 * t + 1] = e1;
  int node0 = b * BSIZE + 2 * t, node1 = b * BSIZE + 2 * t + 1;
  if (node0 < n) { rowptr[node0] = e0; dinv[node0] = rsqrtf((float)(a0 + 1)); }
  if (node1 < n) { rowptr[node1] = e1; dinv[node1] = rsqrtf((float)(a1 + 1)); }
  __syncthreads();
  for (int i = lo + t; i < hi; i += 256) {
    unsigned p = packed[i];
    int j = p >> 17;
    int s = (int)(p & 0x1FFFFu);
    int pos = atomicAdd(&cur[j], 1);  // LDS atomic
    csr_src[pos] = s;
  }
}

// T'[r] = dinv[r] * (X[r] @ W).  One thread per row; W as float4 in LDS.
template <int COUT>
__global__ __launch_bounds__(256) void k_matmul(const float* __restrict__ X,
                                                const float* __restrict__ W,
                                                const float* __restrict__ dinv,
                                                float* __restrict__ T, int n) {
  const int C4 = COUT / 4;
  __shared__ float4 Ws[64 * C4];
  for (int i = threadIdx.x; i < 64 * C4; i += blockDim.x)
    Ws[i] = ((const float4*)W)[i];
  __syncthreads();
  int r = blockIdx.x * blockDim.x + threadIdx.x;
  if (r >= n) return;
  float4 acc[C4];
#pragma unroll
  for (int j = 0; j < C4; ++j) acc[j] = make_float4(0.f, 0.f, 0.f, 0.f);
  const float4* xr = (const float4*)(X + (size_t)r * 64);
#pragma unroll
  for (int k4 = 0; k4 < 16; ++k4) {
    float4 xv = xr[k4];
    const float xs[4] = {xv.x, xv.y, xv.z, xv.w};
#pragma unroll
    for (int c = 0; c < 4; ++c) {
      float xk = xs[c];
      const float4* wrow = &Ws[(k4 * 4 + c) * C4];
#pragma unroll
      for (int j = 0; j < C4; ++j) {
        float4 w = wrow[j];
        acc[j].x = fmaf(xk, w.x, acc[j].x);
        acc[j].y = fmaf(xk, w.y, acc[j].y);
        acc[j].z = fmaf(xk, w.z, acc[j].z);
        acc[j].w = fmaf(xk, w.w, acc[j].w);
      }
    }
  }
  float dr = dinv[r];
  float4* tr = (float4*)(T + (size_t)r * COUT);
#pragma unroll
  for (int j = 0; j < C4; ++j)
    tr[j] = make_float4(acc[j].x * dr, acc[j].y * dr, acc[j].z * dr, acc[j].w * dr);
}

// One wave per dst row: acc = sum T'[src[j]] (batched 8/4/1, independent
// loads), then out = dinv[row]*(acc + T'[row]) + b, optional relu.
template <int COUT, bool RELU>
__global__ __launch_bounds__(256) void k_gather(const float* __restrict__ T,
                                                const int* __restrict__ rowptr,
                                                const int* __restrict__ csr_src,
                                                const float* __restrict__ dinv,
                                                const float* __restrict__ b,
                                                float* __restrict__ out, int n) {
  int wave = blockIdx.x * (blockDim.x >> 6) + (threadIdx.x >> 6);
  int lane = threadIdx.x & 63;
  int row = __builtin_amdgcn_readfirstlane(wave);
  if (row >= n) return;
  int beg = rowptr[row];
  int end = rowptr[row + 1];
  float dr = dinv[row];
  float a0 = 0.f, a1 = 0.f, a2 = 0.f, a3 = 0.f;
  int j = beg;
  if (lane < COUT) {
    for (; j + 8 <= end; j += 8) {
      int s0 = csr_src[j + 0], s1 = csr_src[j + 1], s2 = csr_src[j + 2], s3 = csr_src[j + 3];
      int s4 = csr_src[j + 4], s5 = csr_src[j + 5], s6 = csr_src[j + 6], s7 = csr_src[j + 7];
      float t0 = T[(size_t)s0 * COUT + lane];
      float t1 = T[(size_t)s1 * COUT + lane];
      float t2 = T[(size_t)s2 * COUT + lane];
      float t3 = T[(size_t)s3 * COUT + lane];
      float t4 = T[(size_t)s4 * COUT + lane];
      float t5 = T[(size_t)s5 * COUT + lane];
      float t6 = T[(size_t)s6 * COUT + lane];
      float t7 = T[(size_t)s7 * COUT + lane];
      a0 += t0; a1 += t1; a2 += t2; a3 += t3;
      a0 += t4; a1 += t5; a2 += t6; a3 += t7;
    }
    if (j + 4 <= end) {
      int s0 = csr_src[j + 0], s1 = csr_src[j + 1], s2 = csr_src[j + 2], s3 = csr_src[j + 3];
      float t0 = T[(size_t)s0 * COUT + lane];
      float t1 = T[(size_t)s1 * COUT + lane];
      float t2 = T[(size_t)s2 * COUT + lane];
      float t3 = T[(size_t)s3 * COUT + lane];
      a0 += t0; a1 += t1; a2 += t2; a3 += t3;
      j += 4;
    }
    for (; j < end; ++j) {
      int s = csr_src[j];
      a0 += T[(size_t)s * COUT + lane];
    }
    float acc = (a0 + a1) + (a2 + a3);
    float v = fmaf(dr, acc + T[(size_t)row * COUT + lane], b[lane]);
    if (RELU) v = fmaxf(v, 0.f);
    out[(size_t)row * COUT + lane] = v;
  }
}

extern "C" void kernel_launch(void* const* d_in, const int* in_sizes, int n_in,
                              void* d_out, int out_size, void* d_ws, size_t ws_size,
                              hipStream_t stream) {
  const float* x  = (const float*)d_in[0];
  const void*  ei = d_in[1];
  const float* W1 = (const float*)d_in[2];
  const float* b1 = (const float*)d_in[3];
  const float* W2 = (const float*)d_in[4];
  const float* b2 = (const float*)d_in[5];
  const float* W3 = (const float*)d_in[6];
  const float* b3 = (const float*)d_in[7];
  float* out = (float*)d_out;

  const int n = in_sizes[0] / 64;   // 100000
  const int E = in_sizes[1] / 2;    // 1000000

  const int NB   = (n + BSIZE - 1) / BSIZE;  // 196 buckets
  const int NBLK = (E + CH - 1) / CH;        // 245 edge blocks

  char* ws = (char*)d_ws;
  size_t off = 0;
  auto carve = [&](size_t bytes) -> void* {
    void* p = ws + off;
    off = (off + bytes + 255) & ~(size_t)255;
    return p;
  };
  int*      flag        = (int*)carve(16);
  float*    dinv        = (float*)carve(sizeof(float) * n);
  int*      rowptr      = (int*)carve(sizeof(int) * (n + 1));
  int*      bucket_tot  = (int*)carve(sizeof(int) * 256);
  int*      bucket_base = (int*)carve(sizeof(int) * 257);
  int*      blk_off     = (int*)carve(sizeof(int) * (size_t)NBLK * NB);
  unsigned* packed      = (unsigned*)carve(sizeof(unsigned) * E);
  int*      csr_src     = (int*)carve(sizeof(int) * E);
  float*    T           = (float*)carve(sizeof(float) * (size_t)n * 64);
  float*    A           = (float*)carve(sizeof(float) * (size_t)n * 64);

  const int B = 256;
  const int gN = (n + B - 1) / B;
  const int gW = (n + 3) / 4;  // 4 waves/block, 1 wave/row

  // ---- CSR build (bucket counting sort; no global fine-grained atomics) ----
  k_flag<<<1, 64, 0, stream>>>(ei, flag);
  hipMemsetAsync(bucket_tot, 0, sizeof(int) * NB, stream);
  k_s1<<<NBLK, B, 0, stream>>>(ei, flag, blk_off, bucket_tot, E, NB);
  k_s2a<<<1, B, 0, stream>>>(bucket_tot, bucket_base, rowptr, NB, n, E);
  k_s2b<<<NB, B, 0, stream>>>(blk_off, bucket_base, NBLK, NB);
  k_s3<<<NBLK, B, 0, stream>>>(ei, flag, blk_off, packed, E, NB);
  k_s4<<<NB, B, 0, stream>>>(packed, bucket_base, rowptr, dinv, csr_src, n);

  // ---- layer 1: x -> A ----
  k_matmul<64><<<gN, B, 0, stream>>>(x, W1, dinv, T, n);
  k_gather<64, true><<<gW, B, 0, stream>>>(T, rowptr, csr_src, dinv, b1, A, n);

  // ---- layer 2: A -> A ----
  k_matmul<64><<<gN, B, 0, stream>>>(A, W2, dinv, T, n);
  k_gather<64, true><<<gW, B, 0, stream>>>(T, rowptr, csr_src, dinv, b2, A, n);

  // ---- layer 3: A -> out ----
  k_matmul<32><<<gN, B, 0, stream>>>(A, W3, dinv, T, n);
  k_gather<32, false><<<gW, B, 0, stream>>>(T, rowptr, csr_src, dinv, b3, out, n);
}